// Round 2
// baseline (1010.821 us; speedup 1.0000x reference)
//
#include <hip/hip_runtime.h>
#include <math.h>

// ---------------------------------------------------------------------------
// 2-layer GCN. R14: fix R13's LDS-atomic catastrophe.
// R13 post-mortem: hipcc lowers atomicAdd(float*) on LDS to a ds_read/ds_cmpst
// CAS loop (default IEEE-denorm fp mode) -> ~205 cyc per add, fully serial
// (VALUBusy 1.5%, 700us). Fix: inline-asm ds_add_f32 (native, non-returning,
// exec-masked) on an addrspace(3) pointer; 8 adds share one base VGPR via
// offset: immediates. Structure unchanged from R13 (correctness proven):
//  - scatterA buckets edges by dst>>9 (multisplit, int LDS atomics = native).
//  - degcnt: per-bucket in-degree histogram -> dinv.
//  - agg1_acc: one 1024-thr block per bucket, acc[512][68] fp32 in LDS;
//    8 lanes/edge gather h1s rows (independent uint4 loads), ds_add_f32
//    accumulate; epilogue fuses self-loop + b1 + lrelu + MLP(64->16).
//  - agg2_acc: acc[512][17], 2 lanes/edge, per-thread log_softmax.
// ---------------------------------------------------------------------------

#define CHUNK 4096        // edges per scatterA block
#define BSHIFT 9          // 512 nodes per bucket
#define BMASK 511
#define CAP 9216          // tmp slots per bucket (mean 8192, +11 sigma)
#define ASTRIDE 68        // acc row stride (f32): pad 64->68 for bank spread

typedef __bf16 bf16x8 __attribute__((ext_vector_type(8)));
typedef float f32x4 __attribute__((ext_vector_type(4)));
typedef __attribute__((address_space(3))) float lds_float;

__device__ __forceinline__ unsigned f2b(float f) {  // fp32 -> bf16 bits (RNE)
  unsigned u = __float_as_uint(f);
  return (u + 0x7FFF + ((u >> 16) & 1)) >> 16;
}
__device__ __forceinline__ float blo(unsigned u) { return __uint_as_float(u << 16); }
__device__ __forceinline__ float bhi(unsigned u) { return __uint_as_float(u & 0xffff0000u); }

// 8 native LDS float adds at p[0..7] (one addr VGPR + offset: immediates).
// Non-returning ds_add_f32: no lgkm wait, instructions pipeline back-to-back.
__device__ __forceinline__ void ldsAdd8(float* p, uint4 g) {
  lds_float* lp = (lds_float*)p;
  asm volatile(
      "ds_add_f32 %0, %1\n\t"
      "ds_add_f32 %0, %2 offset:4\n\t"
      "ds_add_f32 %0, %3 offset:8\n\t"
      "ds_add_f32 %0, %4 offset:12\n\t"
      "ds_add_f32 %0, %5 offset:16\n\t"
      "ds_add_f32 %0, %6 offset:20\n\t"
      "ds_add_f32 %0, %7 offset:24\n\t"
      "ds_add_f32 %0, %8 offset:28"
      :
      : "v"(lp), "v"(blo(g.x)), "v"(bhi(g.x)), "v"(blo(g.y)), "v"(bhi(g.y)),
        "v"(blo(g.z)), "v"(bhi(g.z)), "v"(blo(g.w)), "v"(bhi(g.w)));
}

__global__ void binit_kernel(int* __restrict__ gbcursor, int nbc) {
  int b = blockIdx.x * 256 + threadIdx.x;
  if (b < nbc) gbcursor[b] = b * CAP;
}

// Block multisplit: pass1 LDS bucket hist; one global atomic per (block,bucket)
// reserves a segment; pass2 places edges via LDS cursors. pack=(src<<9)|(dst&511).
__global__ __launch_bounds__(256) void scatterA_kernel(const int* __restrict__ src,
                                                       const int* __restrict__ dst,
                                                       int E, int nbc,
                                                       int* __restrict__ gbcursor,
                                                       int* __restrict__ tmp) {
  __shared__ int hist[256];
  __shared__ int segcur[256];
  int tid = threadIdx.x;
  int estart = blockIdx.x * CHUNK;
  int eend = min(E, estart + CHUNK);
  hist[tid] = 0;
  __syncthreads();
  for (int i = estart + tid; i < eend; i += 256)
    atomicAdd(&hist[dst[i] >> BSHIFT], 1);
  __syncthreads();
  if (tid < nbc) {
    int c = hist[tid];
    segcur[tid] = c ? atomicAdd(&gbcursor[tid], c) : 0;
  }
  __syncthreads();
  for (int i = estart + tid; i < eend; i += 256) {
    int d = dst[i];
    int b = d >> BSHIFT;
    int pos = atomicAdd(&segcur[b], 1);
    if (pos < (b + 1) * CAP)  // statistically impossible overflow guard
      tmp[pos] = (src[i] << BSHIFT) | (d & BMASK);
  }
}

// Per-bucket in-degree histogram -> dinv (the only csr-era output still needed).
__global__ __launch_bounds__(512) void degcnt_kernel(const int* __restrict__ tmp,
                                                     const int* __restrict__ gbcursor,
                                                     float* __restrict__ dinv, int n) {
  __shared__ int nh[512];
  int b = blockIdx.x, tid = threadIdx.x;
  nh[tid] = 0;
  __syncthreads();
  int base = b * CAP;
  int count = min(gbcursor[b] - base, CAP);
  for (int i = tid; i < count; i += 512) atomicAdd(&nh[tmp[base + i] & BMASK], 1);
  __syncthreads();
  int v = (b << BSHIFT) + tid;
  if (v < n) dinv[v] = rsqrtf((float)(nh[tid] + 1));
}

// h1s[row] = bf16x2-packed dinv[row] * (x[row] @ W1), via MFMA (R9-proven).
__global__ __launch_bounds__(256, 4) void gemm1_kernel(const float* __restrict__ x,
                                                       const float* __restrict__ W1,
                                                       const float* __restrict__ dinv,
                                                       unsigned* __restrict__ h1s, int n) {
  __shared__ unsigned lds_u[64 * 68 * 2];
  unsigned* xs = lds_u;
  unsigned* wt = lds_u + 64 * 68;
  int tid = threadIdx.x;
  int vb = blockIdx.x * 64;
  int nrows = min(64, n - vb);

  // stage x: coalesced float4 loads, pack to bf16x2
  const float4* xg = (const float4*)(x + (size_t)vb * 128);
#pragma unroll
  for (int it = 0; it < 8; ++it) {
    int idx = it * 256 + tid;
    int r = idx >> 5, c2 = idx & 31;
    float4 vv = make_float4(0.f, 0.f, 0.f, 0.f);
    if (r < nrows) vv = xg[idx];
    xs[r * 68 + c2 * 2] = (f2b(vv.y) << 16) | f2b(vv.x);
    xs[r * 68 + c2 * 2 + 1] = (f2b(vv.w) << 16) | f2b(vv.z);
  }
  // stage W1^T: wt16[n][k] bf16, stride 136 u16 (= 68 u32)
  unsigned short* wt16 = (unsigned short*)wt;
  const float4* wg = (const float4*)W1;
#pragma unroll
  for (int it = 0; it < 8; ++it) {
    int idx = it * 256 + tid;          // [0,2048): k = idx>>4, n0 = (idx&15)*4
    int k = idx >> 4, n0 = (idx & 15) * 4;
    float4 wv = wg[idx];
    wt16[(n0 + 0) * 136 + k] = (unsigned short)f2b(wv.x);
    wt16[(n0 + 1) * 136 + k] = (unsigned short)f2b(wv.y);
    wt16[(n0 + 2) * 136 + k] = (unsigned short)f2b(wv.z);
    wt16[(n0 + 3) * 136 + k] = (unsigned short)f2b(wv.w);
  }
  __syncthreads();

  int lane = tid & 63, wid = tid >> 6;
  int m16 = lane & 15, quad = lane >> 4;
  const unsigned* xp = xs + (wid * 16 + m16) * 68 + quad * 4;
  const unsigned* wp = wt + m16 * 68 + quad * 4;
  f32x4 acc[4] = {};
#pragma unroll
  for (int ks = 0; ks < 4; ++ks) {
    bf16x8 a = *(const bf16x8*)(xp + ks * 16);
#pragma unroll
    for (int nt = 0; nt < 4; ++nt) {
      bf16x8 b = *(const bf16x8*)(wp + nt * 16 * 68 + ks * 16);
      acc[nt] = __builtin_amdgcn_mfma_f32_16x16x32_bf16(a, b, acc[nt], 0, 0, 0);
    }
  }
  // epilogue: C[row = quad*4+reg][col = nt*16+m16]; fold dinv, pack bf16
  int rbase = vb + wid * 16 + quad * 4;
  float dvv[4];
#pragma unroll
  for (int reg = 0; reg < 4; ++reg) {
    int row = rbase + reg;
    dvv[reg] = (row < n) ? dinv[row] : 0.f;
  }
  unsigned short* h16 = (unsigned short*)h1s;
#pragma unroll
  for (int nt = 0; nt < 4; ++nt) {
    int col = nt * 16 + m16;
#pragma unroll
    for (int reg = 0; reg < 4; ++reg) {
      int row = rbase + reg;
      if (row < n)
        h16[(size_t)row * 64 + col] = (unsigned short)f2b(dvv[reg] * acc[nt][reg]);
    }
  }
}

// One 1024-thr block per bucket. Edge phase: 8 lanes/edge (c = uint4 slot),
// independent 16B gathers of h1s[src] -> native ds_add_f32 accumulate on
// acc[d&511][f]. Epilogue: 2 thr/node fuse self-loop + b1 + lrelu + MLP(64->16),
// pack t[v] = bf16(dinv[v] * p).
__global__ __launch_bounds__(1024) void agg1_acc_kernel(const int* __restrict__ tmp,
                                                        const int* __restrict__ gbcursor,
                                                        const uint4* __restrict__ h1s4,
                                                        const float* __restrict__ dinv,
                                                        const float* __restrict__ b1,
                                                        const float* __restrict__ W2,
                                                        unsigned* __restrict__ t, int n) {
  __shared__ float acc[512 * ASTRIDE];   // 139,264 B
  __shared__ float W2s[64 * 16];         // 4 KB
  __shared__ float b1s[64];
  int b = blockIdx.x, tid = threadIdx.x;
  int base = b * CAP;
  int count = min(gbcursor[b] - base, CAP);
  for (int i = tid; i < 512 * ASTRIDE; i += 1024) acc[i] = 0.f;
  W2s[tid] = W2[tid];                    // 64*16 == 1024 == blockDim
  if (tid < 64) b1s[tid] = b1[tid];
  __syncthreads();

  int e = tid >> 3, c = tid & 7;         // 128 edges per pass
#pragma unroll 2
  for (int i = e; i < count; i += 128) {
    int pk = tmp[base + i];
    int s = pk >> BSHIFT, d = pk & BMASK;
    uint4 g = h1s4[(size_t)s * 8 + c];   // 8 lanes -> 128B contiguous row
    ldsAdd8(acc + d * ASTRIDE + c * 8, g);
  }
  __syncthreads();

  // epilogue: thread pair (v2, half); half owns features half*32..+31
  int v2 = tid >> 1, half = tid & 1;
  int v = (b << BSHIFT) + v2;
  bool valid = v < n;
  float dv = valid ? dinv[v] : 0.f;
  const uint4* selfp = h1s4 + (size_t)(valid ? v : 0) * 8 + half * 4;
  const float* arow = acc + v2 * ASTRIDE + half * 32;
  float av[32];
#pragma unroll
  for (int q = 0; q < 4; ++q) {
    uint4 g = selfp[q];
    float4 a0 = *(const float4*)(arow + q * 8);
    float4 a1 = *(const float4*)(arow + q * 8 + 4);
    int fb = half * 32 + q * 8;
    float z;
    z = fmaf(dv, a0.x + blo(g.x), b1s[fb + 0]); av[q * 8 + 0] = fmaxf(z, 0.2f * z);
    z = fmaf(dv, a0.y + bhi(g.x), b1s[fb + 1]); av[q * 8 + 1] = fmaxf(z, 0.2f * z);
    z = fmaf(dv, a0.z + blo(g.y), b1s[fb + 2]); av[q * 8 + 2] = fmaxf(z, 0.2f * z);
    z = fmaf(dv, a0.w + bhi(g.y), b1s[fb + 3]); av[q * 8 + 3] = fmaxf(z, 0.2f * z);
    z = fmaf(dv, a1.x + blo(g.z), b1s[fb + 4]); av[q * 8 + 4] = fmaxf(z, 0.2f * z);
    z = fmaf(dv, a1.y + bhi(g.z), b1s[fb + 5]); av[q * 8 + 5] = fmaxf(z, 0.2f * z);
    z = fmaf(dv, a1.z + blo(g.w), b1s[fb + 6]); av[q * 8 + 6] = fmaxf(z, 0.2f * z);
    z = fmaf(dv, a1.w + bhi(g.w), b1s[fb + 7]); av[q * 8 + 7] = fmaxf(z, 0.2f * z);
  }
  float p[16];
#pragma unroll
  for (int j = 0; j < 16; ++j) p[j] = 0.f;
#pragma unroll
  for (int q = 0; q < 32; ++q) {
    float a = av[q];
    const float4* wr = (const float4*)(W2s + (half * 32 + q) * 16);
    float4 w0 = wr[0], w1 = wr[1], w2v = wr[2], w3 = wr[3];
    p[0] = fmaf(a, w0.x, p[0]);  p[1] = fmaf(a, w0.y, p[1]);
    p[2] = fmaf(a, w0.z, p[2]);  p[3] = fmaf(a, w0.w, p[3]);
    p[4] = fmaf(a, w1.x, p[4]);  p[5] = fmaf(a, w1.y, p[5]);
    p[6] = fmaf(a, w1.z, p[6]);  p[7] = fmaf(a, w1.w, p[7]);
    p[8] = fmaf(a, w2v.x, p[8]); p[9] = fmaf(a, w2v.y, p[9]);
    p[10] = fmaf(a, w2v.z, p[10]); p[11] = fmaf(a, w2v.w, p[11]);
    p[12] = fmaf(a, w3.x, p[12]); p[13] = fmaf(a, w3.y, p[13]);
    p[14] = fmaf(a, w3.z, p[14]); p[15] = fmaf(a, w3.w, p[15]);
  }
#pragma unroll
  for (int j = 0; j < 16; ++j) p[j] += __shfl_xor(p[j], 1, 64);  // pair = lanes 2v2,2v2+1
  if (valid) {
    int jb = half * 8;
    uint4 o;
    o.x = (f2b(dv * p[jb + 1]) << 16) | f2b(dv * p[jb + 0]);
    o.y = (f2b(dv * p[jb + 3]) << 16) | f2b(dv * p[jb + 2]);
    o.z = (f2b(dv * p[jb + 5]) << 16) | f2b(dv * p[jb + 4]);
    o.w = (f2b(dv * p[jb + 7]) << 16) | f2b(dv * p[jb + 6]);
    ((uint4*)t)[(size_t)v * 2 + half] = o;
  }
}

// Same structure for layer 2: 2 lanes/edge (32B t rows), acc[512][17] (stride 17
// is odd -> bank=(17d+f)%32 uniform). Epilogue: 1 thr/node log_softmax.
__global__ __launch_bounds__(1024) void agg2_acc_kernel(const int* __restrict__ tmp,
                                                        const int* __restrict__ gbcursor,
                                                        const uint4* __restrict__ t4,
                                                        const float* __restrict__ dinv,
                                                        const float* __restrict__ b2,
                                                        float* __restrict__ out, int n) {
  __shared__ float acc[512 * 17];
  int b = blockIdx.x, tid = threadIdx.x;
  int base = b * CAP;
  int count = min(gbcursor[b] - base, CAP);
  for (int i = tid; i < 512 * 17; i += 1024) acc[i] = 0.f;
  __syncthreads();

  int e = tid >> 1, c = tid & 1;         // 512 edges per pass
#pragma unroll 2
  for (int i = e; i < count; i += 512) {
    int pk = tmp[base + i];
    int s = pk >> BSHIFT, d = pk & BMASK;
    uint4 g = t4[(size_t)s * 2 + c];
    ldsAdd8(acc + d * 17 + c * 8, g);
  }
  __syncthreads();

  if (tid < 512) {
    int v = (b << BSHIFT) + tid;
    if (v < n) {
      float dv = dinv[v];
      uint4 g0 = t4[(size_t)v * 2];
      uint4 g1 = t4[(size_t)v * 2 + 1];
      const float* ar = acc + tid * 17;
      float4 bb0 = ((const float4*)b2)[0], bb1 = ((const float4*)b2)[1];
      float4 bb2 = ((const float4*)b2)[2], bb3 = ((const float4*)b2)[3];
      float z[16];
      z[0] = fmaf(dv, ar[0] + blo(g0.x), bb0.x);
      z[1] = fmaf(dv, ar[1] + bhi(g0.x), bb0.y);
      z[2] = fmaf(dv, ar[2] + blo(g0.y), bb0.z);
      z[3] = fmaf(dv, ar[3] + bhi(g0.y), bb0.w);
      z[4] = fmaf(dv, ar[4] + blo(g0.z), bb1.x);
      z[5] = fmaf(dv, ar[5] + bhi(g0.z), bb1.y);
      z[6] = fmaf(dv, ar[6] + blo(g0.w), bb1.z);
      z[7] = fmaf(dv, ar[7] + bhi(g0.w), bb1.w);
      z[8] = fmaf(dv, ar[8] + blo(g1.x), bb2.x);
      z[9] = fmaf(dv, ar[9] + bhi(g1.x), bb2.y);
      z[10] = fmaf(dv, ar[10] + blo(g1.y), bb2.z);
      z[11] = fmaf(dv, ar[11] + bhi(g1.y), bb2.w);
      z[12] = fmaf(dv, ar[12] + blo(g1.z), bb3.x);
      z[13] = fmaf(dv, ar[13] + bhi(g1.z), bb3.y);
      z[14] = fmaf(dv, ar[14] + blo(g1.w), bb3.z);
      z[15] = fmaf(dv, ar[15] + bhi(g1.w), bb3.w);
      float mx = z[0];
#pragma unroll
      for (int q = 1; q < 16; ++q) mx = fmaxf(mx, z[q]);
      float ss = 0.f;
#pragma unroll
      for (int q = 0; q < 16; ++q) ss += expf(z[q] - mx);
      float lg = mx + logf(ss);
      float4* o = (float4*)out + (size_t)v * 4;
      o[0] = make_float4(z[0] - lg, z[1] - lg, z[2] - lg, z[3] - lg);
      o[1] = make_float4(z[4] - lg, z[5] - lg, z[6] - lg, z[7] - lg);
      o[2] = make_float4(z[8] - lg, z[9] - lg, z[10] - lg, z[11] - lg);
      o[3] = make_float4(z[12] - lg, z[13] - lg, z[14] - lg, z[15] - lg);
    }
  }
}

extern "C" void kernel_launch(void* const* d_in, const int* in_sizes, int n_in,
                              void* d_out, int out_size, void* d_ws, size_t ws_size,
                              hipStream_t stream) {
  const float* x = (const float*)d_in[0];
  const int* edge_index = (const int*)d_in[1];
  const float* W1 = (const float*)d_in[2];
  const float* b1 = (const float*)d_in[3];
  const float* W2 = (const float*)d_in[4];
  const float* b2 = (const float*)d_in[5];
  float* out = (float*)d_out;

  int N_ = in_sizes[0] / 128;
  int E_ = in_sizes[1] / 2;
  const int* src = edge_index;
  const int* dst = edge_index + E_;
  int NBc = (N_ + BMASK) >> BSHIFT;  // 196 buckets of 512 nodes (<= 256)

  char* ws = (char*)d_ws;
  size_t off = 0;
  auto take = [&](size_t bytes) {
    void* p = ws + off;
    off += (bytes + 255) & ~(size_t)255;
    return p;
  };
  unsigned* h1s = (unsigned*)take((size_t)N_ * 32 * 4);
  int* tmp = (int*)take((size_t)NBc * CAP * 4);      // live until agg2
  unsigned* t = (unsigned*)take((size_t)N_ * 8 * 4);
  float* dinv = (float*)take((size_t)N_ * 4);
  int* gbcursor = (int*)take((size_t)NBc * 4);
  (void)ws_size;

  binit_kernel<<<(NBc + 255) / 256, 256, 0, stream>>>(gbcursor, NBc);
  scatterA_kernel<<<(E_ + CHUNK - 1) / CHUNK, 256, 0, stream>>>(src, dst, E_, NBc,
                                                                gbcursor, tmp);
  degcnt_kernel<<<NBc, 512, 0, stream>>>(tmp, gbcursor, dinv, N_);
  gemm1_kernel<<<(N_ + 63) / 64, 256, 0, stream>>>(x, W1, dinv, h1s, N_);
  agg1_acc_kernel<<<NBc, 1024, 0, stream>>>(tmp, gbcursor, (const uint4*)h1s, dinv,
                                            b1, W2, t, N_);
  agg2_acc_kernel<<<NBc, 1024, 0, stream>>>(tmp, gbcursor, (const uint4*)t, dinv,
                                            b2, out, N_);
}

// Round 3
// 361.147 us; speedup vs baseline: 2.7989x; 2.7989x over previous
//
#include <hip/hip_runtime.h>
#include <math.h>

// ---------------------------------------------------------------------------
// 2-layer GCN. R15: abandon LDS-atomic aggregation (R13/R14 post-mortem:
// native ds_add_f32 measures ~205 cyc per wave64 instr on gfx950 -- the DS
// unit serializes ~3.2 cyc/lane-atomic; 16 waves x 64 iters x 8 instrs x 205
// = 1.68M cyc = the observed 700us, with VALUBusy=HBM=1.5%).
// Back to the R12 CSR-walk aggregation (proven 48us agg1), with two fixes:
//  - CSR build via GLOBAL atomics (degcount -> block scan -> scatter with
//    atomic cursor). ~E total L2 atomics replaces the multisplit+512-scan
//    pipeline (LDS atomics + 18 barriers on 1024 threads).
//  - agg1/agg2 walk de-serialized: for deg<=32, load all csr entries up
//    front, then issue 8 (resp 4) independent uint4 gathers before any
//    accumulate (R12 held ~1.3 gathers in flight -> 23% HBM). Masked slots
//    gather the zero row (L1-cached). deg>32 tail = old while loop.
// ---------------------------------------------------------------------------

typedef __bf16 bf16x8 __attribute__((ext_vector_type(8)));
typedef float f32x4 __attribute__((ext_vector_type(4)));

__device__ __forceinline__ unsigned f2b(float f) {  // fp32 -> bf16 bits (RNE)
  unsigned u = __float_as_uint(f);
  return (u + 0x7FFF + ((u >> 16) & 1)) >> 16;
}

struct f2 { float x, y; };
__device__ __forceinline__ void addu(f2& a, unsigned u) {
  a.x += __uint_as_float(u << 16);
  a.y += __uint_as_float(u & 0xffff0000u);
}
__device__ __forceinline__ void addu4(f2* a, uint4 g) {
  addu(a[0], g.x); addu(a[1], g.y); addu(a[2], g.z); addu(a[3], g.w);
}

// zero deg[] + the zero rows of h1s and t (masked-gather targets)
__global__ void zinit_kernel(int* __restrict__ deg, int n,
                             unsigned* __restrict__ h1s, unsigned* __restrict__ t) {
  for (int i = blockIdx.x * 256 + threadIdx.x; i < n; i += gridDim.x * 256) deg[i] = 0;
  if (blockIdx.x == 0) {
    if (threadIdx.x < 32) h1s[(size_t)n * 32 + threadIdx.x] = 0u;
    else if (threadIdx.x < 40) t[(size_t)n * 8 + (threadIdx.x - 32)] = 0u;
  }
}

// in-degree histogram: E global int atomics over a 400KB (L2-resident) array
__global__ __launch_bounds__(256) void degcount_kernel(const int* __restrict__ dst,
                                                       int E, int* __restrict__ deg) {
  int i = blockIdx.x * 256 + threadIdx.x;
  if (i < E) atomicAdd(&deg[dst[i]], 1);
}

// block-local exclusive scan of deg (1024/block) + per-block totals
__global__ __launch_bounds__(1024) void scanA_kernel(const int* __restrict__ deg, int n,
                                                     int* __restrict__ row_start,
                                                     int* __restrict__ blocksum) {
  __shared__ int sc[1024];
  int tid = threadIdx.x;
  int v = blockIdx.x * 1024 + tid;
  int d = (v < n) ? deg[v] : 0;
  sc[tid] = d;
  __syncthreads();
  for (int off = 1; off < 1024; off <<= 1) {
    int a = sc[tid];
    int b = (tid >= off) ? sc[tid - off] : 0;
    __syncthreads();
    sc[tid] = a + b;
    __syncthreads();
  }
  if (v < n) row_start[v] = sc[tid] - d;  // block-local exclusive
  if (tid == 1023) blocksum[blockIdx.x] = sc[1023];
}

// add block offsets; emit cursor (= row_start copy for scatter) and dinv
__global__ __launch_bounds__(1024) void scanC_kernel(const int* __restrict__ deg, int n,
                                                     int nb, const int* __restrict__ blocksum,
                                                     int* __restrict__ row_start,
                                                     int* __restrict__ cursor,
                                                     float* __restrict__ dinv) {
  __shared__ int bs[128];
  int tid = threadIdx.x, b = blockIdx.x;
  if (tid < nb) bs[tid] = blocksum[tid];
  __syncthreads();
  int off = 0;
  for (int jj = 0; jj < b; ++jj) off += bs[jj];  // broadcast LDS reads
  int v = b * 1024 + tid;
  if (v < n) {
    int rs = row_start[v] + off;
    row_start[v] = rs;
    cursor[v] = rs;
    dinv[v] = rsqrtf((float)(deg[v] + 1));
  }
}

// CSR fill: one returning global atomic per edge (L2), scattered 4B write
__global__ __launch_bounds__(256) void scatter_kernel(const int* __restrict__ src,
                                                      const int* __restrict__ dst,
                                                      int E, int* __restrict__ cursor,
                                                      int* __restrict__ csr) {
  int i = blockIdx.x * 256 + threadIdx.x;
  if (i < E) {
    int pos = atomicAdd(&cursor[dst[i]], 1);
    csr[pos] = src[i];
  }
}

// h1s[row] = bf16x2-packed dinv[row] * (x[row] @ W1), via MFMA (R9-proven).
__global__ __launch_bounds__(256, 4) void gemm1_kernel(const float* __restrict__ x,
                                                       const float* __restrict__ W1,
                                                       const float* __restrict__ dinv,
                                                       unsigned* __restrict__ h1s, int n) {
  __shared__ unsigned lds_u[64 * 68 * 2];
  unsigned* xs = lds_u;
  unsigned* wt = lds_u + 64 * 68;
  int tid = threadIdx.x;
  int vb = blockIdx.x * 64;
  int nrows = min(64, n - vb);

  const float4* xg = (const float4*)(x + (size_t)vb * 128);
#pragma unroll
  for (int it = 0; it < 8; ++it) {
    int idx = it * 256 + tid;
    int r = idx >> 5, c2 = idx & 31;
    float4 vv = make_float4(0.f, 0.f, 0.f, 0.f);
    if (r < nrows) vv = xg[idx];
    xs[r * 68 + c2 * 2] = (f2b(vv.y) << 16) | f2b(vv.x);
    xs[r * 68 + c2 * 2 + 1] = (f2b(vv.w) << 16) | f2b(vv.z);
  }
  unsigned short* wt16 = (unsigned short*)wt;
  const float4* wg = (const float4*)W1;
#pragma unroll
  for (int it = 0; it < 8; ++it) {
    int idx = it * 256 + tid;          // k = idx>>4, n0 = (idx&15)*4
    int k = idx >> 4, n0 = (idx & 15) * 4;
    float4 wv = wg[idx];
    wt16[(n0 + 0) * 136 + k] = (unsigned short)f2b(wv.x);
    wt16[(n0 + 1) * 136 + k] = (unsigned short)f2b(wv.y);
    wt16[(n0 + 2) * 136 + k] = (unsigned short)f2b(wv.z);
    wt16[(n0 + 3) * 136 + k] = (unsigned short)f2b(wv.w);
  }
  __syncthreads();

  int lane = tid & 63, wid = tid >> 6;
  int m16 = lane & 15, quad = lane >> 4;
  const unsigned* xp = xs + (wid * 16 + m16) * 68 + quad * 4;
  const unsigned* wp = wt + m16 * 68 + quad * 4;
  f32x4 acc[4] = {};
#pragma unroll
  for (int ks = 0; ks < 4; ++ks) {
    bf16x8 a = *(const bf16x8*)(xp + ks * 16);
#pragma unroll
    for (int nt = 0; nt < 4; ++nt) {
      bf16x8 b = *(const bf16x8*)(wp + nt * 16 * 68 + ks * 16);
      acc[nt] = __builtin_amdgcn_mfma_f32_16x16x32_bf16(a, b, acc[nt], 0, 0, 0);
    }
  }
  int rbase = vb + wid * 16 + quad * 4;
  float dvv[4];
#pragma unroll
  for (int reg = 0; reg < 4; ++reg) {
    int row = rbase + reg;
    dvv[reg] = (row < n) ? dinv[row] : 0.f;
  }
  unsigned short* h16 = (unsigned short*)h1s;
#pragma unroll
  for (int nt = 0; nt < 4; ++nt) {
    int col = nt * 16 + m16;
#pragma unroll
    for (int reg = 0; reg < 4; ++reg) {
      int row = rbase + reg;
      if (row < n)
        h16[(size_t)row * 64 + col] = (unsigned short)f2b(dvv[reg] * acc[nt][reg]);
    }
  }
}

// Half-wave per node: lanes 0-31 node A, 32-63 node B. sub=lane&31:
// e=sub>>3 in [0,4), c=sub&7. Fast path deg<=32: 8 csr loads up front, then
// 8 independent uint4 gathers (masked -> zero row n, L1-hit). Tail while for
// deg>32 (P~1e-4). Grid-stride, 8 nodes/block.
__global__ __launch_bounds__(256) void agg1_kernel(const uint4* __restrict__ h1s4,
                                                   const float* __restrict__ dinv,
                                                   const int* __restrict__ row_start,
                                                   const int* __restrict__ degs,
                                                   const int* __restrict__ csr,
                                                   const float* __restrict__ b1,
                                                   const float* __restrict__ W2,
                                                   unsigned* __restrict__ t, int n) {
  __shared__ float W2s[64 * 17];
  __shared__ float b1s[64];
  __shared__ float a_s[4][2][64];
  for (int i = threadIdx.x; i < 1024; i += 256)
    W2s[(i >> 4) * 17 + (i & 15)] = W2[i];
  if (threadIdx.x < 64) b1s[threadIdx.x] = b1[threadIdx.x];
  __syncthreads();

  int wave = threadIdx.x >> 6, lane = threadIdx.x & 63;
  int half = lane >> 5, sub = lane & 31;
  int e = sub >> 3, c = sub & 7;
  int j = sub & 15, grp = (sub >> 4) & 1;

  for (int vbase = blockIdx.x * 8; vbase < n; vbase += gridDim.x * 8) {
    int v = vbase + wave * 2 + half;
    bool valid = (v < n);            // half-uniform
    int vc = valid ? v : 0;
    int rs = row_start[vc];
    int deg = valid ? degs[vc] : 0;
    int e1 = rs + deg;
    float dv = valid ? dinv[vc] : 0.f;

    f2 a0[4];
#pragma unroll
    for (int k = 0; k < 4; ++k) a0[k] = {0.f, 0.f};
    {  // self loop: e==0 lanes pull row v, others pull zero row
      int s = (valid && sub < 8) ? v : n;
      addu4(a0, h1s4[(size_t)s * 8 + c]);
    }
    // fast path: all csr entries for deg<=32 (padded reads safe), then
    // 8 independent gathers
    int cv0[4], cv1[4];
#pragma unroll
    for (int it = 0; it < 4; ++it) {
      cv0[it] = csr[rs + it * 8 + e];
      cv1[it] = csr[rs + it * 8 + 4 + e];
    }
    uint4 g[8];
#pragma unroll
    for (int it = 0; it < 4; ++it) {
      int k0 = rs + it * 8 + e, k1 = k0 + 4;
      int s0 = (k0 < e1) ? cv0[it] : n;
      int s1 = (k1 < e1) ? cv1[it] : n;
      g[2 * it] = h1s4[(size_t)s0 * 8 + c];
      g[2 * it + 1] = h1s4[(size_t)s1 * 8 + c];
    }
#pragma unroll
    for (int k = 0; k < 8; ++k) addu4(a0, g[k]);
    // tail: deg > 32 (rare)
    int i = rs + 32;
    while (__any(i < e1)) {
      int i0 = i + e, i1 = i + 4 + e;
      int s0v = csr[i0];
      int s1v = csr[i1];
      int s0 = (i0 < e1) ? s0v : n;
      int s1 = (i1 < e1) ? s1v : n;
      addu4(a0, h1s4[(size_t)s0 * 8 + c]);
      addu4(a0, h1s4[(size_t)s1 * 8 + c]);
      i += 8;
    }
    // reduce across e (lane bits 3,4 within half): 2 levels
#pragma unroll
    for (int m = 8; m <= 16; m <<= 1) {
#pragma unroll
      for (int k = 0; k < 4; ++k) {
        a0[k].x += __shfl_xor(a0[k].x, m, 64);
        a0[k].y += __shfl_xor(a0[k].y, m, 64);
      }
    }
    if (sub < 8) {  // e==0; c==sub; features 8c..8c+7
#pragma unroll
      for (int k = 0; k < 4; ++k) {
        float z0 = fmaf(dv, a0[k].x, b1s[8 * sub + 2 * k]);
        float z1 = fmaf(dv, a0[k].y, b1s[8 * sub + 2 * k + 1]);
        a_s[wave][half][8 * sub + 2 * k] = fmaxf(z0, 0.2f * z0);
        a_s[wave][half][8 * sub + 2 * k + 1] = fmaxf(z1, 0.2f * z1);
      }
    }
    // MLP 64->16: each half-lane sums 32 features (grp*16 and 32+grp*16)
    float p = 0.f;
#pragma unroll
    for (int q = 0; q < 16; ++q) {
      int f = grp * 16 + q;
      p = fmaf(a_s[wave][half][f], W2s[f * 17 + j], p);
    }
#pragma unroll
    for (int q = 0; q < 16; ++q) {
      int f = 32 + grp * 16 + q;
      p = fmaf(a_s[wave][half][f], W2s[f * 17 + j], p);
    }
    p += __shfl_xor(p, 16, 64);  // combine grp halves (lane bit 4)
    float pv = dv * p;
    float po = __shfl_xor(pv, 1, 64);
    if (valid && sub < 16 && !(sub & 1))
      t[(size_t)v * 8 + (sub >> 1)] = (f2b(po) << 16) | f2b(pv);
  }
}

// 16 lanes per node, bf16 t rows (32B). sub=lane&15: e=sub>>1 (8 edge slots),
// c=sub&1. Fast path deg<=32: 4 csr loads + 4 independent gathers. Row n of t
// is zeros. log_softmax via 8-local + xor-1 lane reduce.
__global__ __launch_bounds__(256) void agg2_kernel(const uint4* __restrict__ t4,
                                                   const float* __restrict__ dinv,
                                                   const int* __restrict__ row_start,
                                                   const int* __restrict__ degs,
                                                   const int* __restrict__ csr,
                                                   const float* __restrict__ b2,
                                                   float* __restrict__ out, int n) {
  int idx = blockIdx.x * 256 + threadIdx.x;
  int v = idx >> 4;
  if (v >= n) return;
  int sub = threadIdx.x & 15;
  int e = sub >> 1, c = sub & 1;
  float dv = dinv[v];
  int rs = row_start[v], e1 = rs + degs[v];
  f2 A0[4];
#pragma unroll
  for (int k = 0; k < 4; ++k) A0[k] = {0.f, 0.f};
  {  // self loop
    int s = (e == 0) ? v : n;
    addu4(A0, t4[(size_t)s * 2 + c]);
  }
  int cv[4];
#pragma unroll
  for (int it = 0; it < 4; ++it) cv[it] = csr[rs + it * 8 + e];
  uint4 g[4];
#pragma unroll
  for (int it = 0; it < 4; ++it) {
    int k = rs + it * 8 + e;
    int s = (k < e1) ? cv[it] : n;
    g[it] = t4[(size_t)s * 2 + c];
  }
#pragma unroll
  for (int k = 0; k < 4; ++k) addu4(A0, g[k]);
  // tail: deg > 32 (rare; node-uniform)
  int i = rs + 32;
  while (i < e1) {
    int i0 = i + e;
    int sv = csr[i0];
    int s = (i0 < e1) ? sv : n;
    addu4(A0, t4[(size_t)s * 2 + c]);
    i += 8;
  }
#pragma unroll
  for (int m = 2; m <= 8; m <<= 1) {  // reduce across e-groups (sub bits 1..3)
#pragma unroll
    for (int k = 0; k < 4; ++k) {
      A0[k].x += __shfl_xor(A0[k].x, m, 64);
      A0[k].y += __shfl_xor(A0[k].y, m, 64);
    }
  }
  float4 bb0 = ((const float4*)b2)[c * 2];
  float4 bb1 = ((const float4*)b2)[c * 2 + 1];
  float z[8];
  z[0] = fmaf(dv, A0[0].x, bb0.x); z[1] = fmaf(dv, A0[0].y, bb0.y);
  z[2] = fmaf(dv, A0[1].x, bb0.z); z[3] = fmaf(dv, A0[1].y, bb0.w);
  z[4] = fmaf(dv, A0[2].x, bb1.x); z[5] = fmaf(dv, A0[2].y, bb1.y);
  z[6] = fmaf(dv, A0[3].x, bb1.z); z[7] = fmaf(dv, A0[3].y, bb1.w);
  float mx = z[0];
#pragma unroll
  for (int q = 1; q < 8; ++q) mx = fmaxf(mx, z[q]);
  mx = fmaxf(mx, __shfl_xor(mx, 1, 64));  // combine c halves
  float ss = 0.f;
#pragma unroll
  for (int q = 0; q < 8; ++q) ss += expf(z[q] - mx);
  ss += __shfl_xor(ss, 1, 64);
  float lg = mx + logf(ss);
  if (e == 0) {
    float4 r0 = make_float4(z[0] - lg, z[1] - lg, z[2] - lg, z[3] - lg);
    float4 r1 = make_float4(z[4] - lg, z[5] - lg, z[6] - lg, z[7] - lg);
    float4* o = (float4*)out + (size_t)v * 4 + c * 2;
    o[0] = r0;
    o[1] = r1;
  }
}

extern "C" void kernel_launch(void* const* d_in, const int* in_sizes, int n_in,
                              void* d_out, int out_size, void* d_ws, size_t ws_size,
                              hipStream_t stream) {
  const float* x = (const float*)d_in[0];
  const int* edge_index = (const int*)d_in[1];
  const float* W1 = (const float*)d_in[2];
  const float* b1 = (const float*)d_in[3];
  const float* W2 = (const float*)d_in[4];
  const float* b2 = (const float*)d_in[5];
  float* out = (float*)d_out;

  int N_ = in_sizes[0] / 128;
  int E_ = in_sizes[1] / 2;
  const int* src = edge_index;
  const int* dst = edge_index + E_;
  int NBLK = (N_ + 1023) >> 10;  // scan blocks (98 for N=100k)

  char* ws = (char*)d_ws;
  size_t off = 0;
  auto take = [&](size_t bytes) {
    void* p = ws + off;
    off += (bytes + 255) & ~(size_t)255;
    return p;
  };
  unsigned* h1s = (unsigned*)take(((size_t)N_ + 1) * 32 * 4);  // +1 zero row
  unsigned* t = (unsigned*)take(((size_t)N_ + 1) * 8 * 4);     // +1 zero row
  float* dinv = (float*)take((size_t)N_ * 4);
  int* deg = (int*)take((size_t)N_ * 4);
  int* row_start = (int*)take((size_t)N_ * 4);
  int* cursor = (int*)take((size_t)N_ * 4);
  int* csr = (int*)take(((size_t)E_ + 64) * 4);  // +pad for fast-path overreads
  int* blocksum = (int*)take(128 * 4);
  (void)ws_size;

  zinit_kernel<<<512, 256, 0, stream>>>(deg, N_, h1s, t);
  degcount_kernel<<<(E_ + 255) / 256, 256, 0, stream>>>(dst, E_, deg);
  scanA_kernel<<<NBLK, 1024, 0, stream>>>(deg, N_, row_start, blocksum);
  scanC_kernel<<<NBLK, 1024, 0, stream>>>(deg, N_, NBLK, blocksum, row_start,
                                          cursor, dinv);
  scatter_kernel<<<(E_ + 255) / 256, 256, 0, stream>>>(src, dst, E_, cursor, csr);
  gemm1_kernel<<<(N_ + 63) / 64, 256, 0, stream>>>(x, W1, dinv, h1s, N_);
  agg1_kernel<<<2048, 256, 0, stream>>>((const uint4*)h1s, dinv, row_start, deg,
                                        csr, b1, W2, t, N_);
  agg2_kernel<<<(N_ * 16 + 255) / 256, 256, 0, stream>>>((const uint4*)t, dinv,
                                                         row_start, deg, csr,
                                                         b2, out, N_);
}

// Round 4
// 200.363 us; speedup vs baseline: 5.0449x; 1.8025x over previous
//
#include <hip/hip_runtime.h>
#include <math.h>

// ---------------------------------------------------------------------------
// 2-layer GCN. R16: fuse CSR-build into agg1; purge per-edge global atomics.
// R15 post-mortem: scatter_kernel wrote 105MB for a 6.4MB csr (random 4B
// writes -> full-line writebacks, 130us) and degcount's 1.6M random global
// atomics ate ~100us. Proven-fast primitives only:
//  - scatterA (R12): multisplit by dst>>9 into tmp; segment-coalesced writes,
//    2 LDS atomics/edge + 77K global atomics total.
//  - degcnt (R13): per-bucket hist -> dinv (needed by gemm1).
//  - agg1_fused (NEW): one 1024-thr block per bucket. Build bucket-local CSR
//    in LDS (hist -> 512-scan -> LDS-cursor scatter, ~2 LDS atomics/edge),
//    dump csr/row_start/deg coalesced for agg2, then walk: half-wave per
//    node, 8 independent uint4 gathers in flight (deg<=32 fast path), csr
//    reads from LDS, register accumulation, fused b1+lrelu+MLP(64->16)
//    epilogue -> t (bf16).
//  - agg2 (R15): node-parallel 16 lanes/node, 4 gathers in flight, padded csr.
// ---------------------------------------------------------------------------

#define CHUNK 4096        // edges per scatterA block
#define BSHIFT 9          // 512 nodes per bucket
#define BMASK 511
#define CAP 9216          // tmp/csr slots per bucket (mean 8192, +11 sigma)
#define CAPP (CAP + 40)   // LDS csr with fast-path overread pad

typedef __bf16 bf16x8 __attribute__((ext_vector_type(8)));
typedef float f32x4 __attribute__((ext_vector_type(4)));

__device__ __forceinline__ unsigned f2b(float f) {  // fp32 -> bf16 bits (RNE)
  unsigned u = __float_as_uint(f);
  return (u + 0x7FFF + ((u >> 16) & 1)) >> 16;
}

struct f2 { float x, y; };
__device__ __forceinline__ void addu(f2& a, unsigned u) {
  a.x += __uint_as_float(u << 16);
  a.y += __uint_as_float(u & 0xffff0000u);
}
__device__ __forceinline__ void addu4(f2* a, uint4 g) {
  addu(a[0], g.x); addu(a[1], g.y); addu(a[2], g.z); addu(a[3], g.w);
}

// init bucket cursors + zero rows n of h1s and t (masked-gather targets)
__global__ void binit_kernel(int* __restrict__ gbcursor, int nbc,
                             unsigned* __restrict__ h1s, unsigned* __restrict__ t,
                             int n) {
  int b = blockIdx.x * 256 + threadIdx.x;
  if (b < nbc) gbcursor[b] = b * CAP;
  if (blockIdx.x == 0) {
    if (threadIdx.x < 32) h1s[(size_t)n * 32 + threadIdx.x] = 0u;
    else if (threadIdx.x < 40) t[(size_t)n * 8 + (threadIdx.x - 32)] = 0u;
  }
}

// Block multisplit: pass1 LDS bucket hist; one global atomic per (block,bucket)
// reserves a segment; pass2 places edges via LDS cursors. pack=(src<<9)|(dst&511).
__global__ __launch_bounds__(256) void scatterA_kernel(const int* __restrict__ src,
                                                       const int* __restrict__ dst,
                                                       int E, int nbc,
                                                       int* __restrict__ gbcursor,
                                                       int* __restrict__ tmp) {
  __shared__ int hist[256];
  __shared__ int segcur[256];
  int tid = threadIdx.x;
  int estart = blockIdx.x * CHUNK;
  int eend = min(E, estart + CHUNK);
  hist[tid] = 0;
  __syncthreads();
  for (int i = estart + tid; i < eend; i += 256)
    atomicAdd(&hist[dst[i] >> BSHIFT], 1);
  __syncthreads();
  if (tid < nbc) {
    int c = hist[tid];
    segcur[tid] = c ? atomicAdd(&gbcursor[tid], c) : 0;
  }
  __syncthreads();
  for (int i = estart + tid; i < eend; i += 256) {
    int d = dst[i];
    int b = d >> BSHIFT;
    int pos = atomicAdd(&segcur[b], 1);
    if (pos < (b + 1) * CAP)  // statistically impossible overflow guard
      tmp[pos] = (src[i] << BSHIFT) | (d & BMASK);
  }
}

// Per-bucket in-degree histogram -> dinv (needed by gemm1 before agg1).
__global__ __launch_bounds__(512) void degcnt_kernel(const int* __restrict__ tmp,
                                                     const int* __restrict__ gbcursor,
                                                     float* __restrict__ dinv, int n) {
  __shared__ int nh[512];
  int b = blockIdx.x, tid = threadIdx.x;
  nh[tid] = 0;
  __syncthreads();
  int base = b * CAP;
  int count = min(gbcursor[b] - base, CAP);
  for (int i = tid; i < count; i += 512) atomicAdd(&nh[tmp[base + i] & BMASK], 1);
  __syncthreads();
  int v = (b << BSHIFT) + tid;
  if (v < n) dinv[v] = rsqrtf((float)(nh[tid] + 1));
}

// h1s[row] = bf16x2-packed dinv[row] * (x[row] @ W1), via MFMA (R9-proven).
__global__ __launch_bounds__(256, 4) void gemm1_kernel(const float* __restrict__ x,
                                                       const float* __restrict__ W1,
                                                       const float* __restrict__ dinv,
                                                       unsigned* __restrict__ h1s, int n) {
  __shared__ unsigned lds_u[64 * 68 * 2];
  unsigned* xs = lds_u;
  unsigned* wt = lds_u + 64 * 68;
  int tid = threadIdx.x;
  int vb = blockIdx.x * 64;
  int nrows = min(64, n - vb);

  const float4* xg = (const float4*)(x + (size_t)vb * 128);
#pragma unroll
  for (int it = 0; it < 8; ++it) {
    int idx = it * 256 + tid;
    int r = idx >> 5, c2 = idx & 31;
    float4 vv = make_float4(0.f, 0.f, 0.f, 0.f);
    if (r < nrows) vv = xg[idx];
    xs[r * 68 + c2 * 2] = (f2b(vv.y) << 16) | f2b(vv.x);
    xs[r * 68 + c2 * 2 + 1] = (f2b(vv.w) << 16) | f2b(vv.z);
  }
  unsigned short* wt16 = (unsigned short*)wt;
  const float4* wg = (const float4*)W1;
#pragma unroll
  for (int it = 0; it < 8; ++it) {
    int idx = it * 256 + tid;          // k = idx>>4, n0 = (idx&15)*4
    int k = idx >> 4, n0 = (idx & 15) * 4;
    float4 wv = wg[idx];
    wt16[(n0 + 0) * 136 + k] = (unsigned short)f2b(wv.x);
    wt16[(n0 + 1) * 136 + k] = (unsigned short)f2b(wv.y);
    wt16[(n0 + 2) * 136 + k] = (unsigned short)f2b(wv.z);
    wt16[(n0 + 3) * 136 + k] = (unsigned short)f2b(wv.w);
  }
  __syncthreads();

  int lane = tid & 63, wid = tid >> 6;
  int m16 = lane & 15, quad = lane >> 4;
  const unsigned* xp = xs + (wid * 16 + m16) * 68 + quad * 4;
  const unsigned* wp = wt + m16 * 68 + quad * 4;
  f32x4 acc[4] = {};
#pragma unroll
  for (int ks = 0; ks < 4; ++ks) {
    bf16x8 a = *(const bf16x8*)(xp + ks * 16);
#pragma unroll
    for (int nt = 0; nt < 4; ++nt) {
      bf16x8 b = *(const bf16x8*)(wp + nt * 16 * 68 + ks * 16);
      acc[nt] = __builtin_amdgcn_mfma_f32_16x16x32_bf16(a, b, acc[nt], 0, 0, 0);
    }
  }
  int rbase = vb + wid * 16 + quad * 4;
  float dvv[4];
#pragma unroll
  for (int reg = 0; reg < 4; ++reg) {
    int row = rbase + reg;
    dvv[reg] = (row < n) ? dinv[row] : 0.f;
  }
  unsigned short* h16 = (unsigned short*)h1s;
#pragma unroll
  for (int nt = 0; nt < 4; ++nt) {
    int col = nt * 16 + m16;
#pragma unroll
    for (int reg = 0; reg < 4; ++reg) {
      int row = rbase + reg;
      if (row < n)
        h16[(size_t)row * 64 + col] = (unsigned short)f2b(dvv[reg] * acc[nt][reg]);
    }
  }
}

// One 1024-thr block per bucket: build LDS csr (hist -> scan -> scatter),
// dump csr/row_start/deg (coalesced), then walk with register accumulation.
// Walk: half-wave per node (lanes 0-31 node A, 32-63 node B); sub=lane&31,
// e=sub>>3, c=sub&7. Fast path deg<=32: 8 independent uint4 gathers; masked
// slots pull zero row n. Epilogue fuses b1 + lrelu + MLP(64->16) -> t bf16.
__global__ __launch_bounds__(1024) void agg1_fused_kernel(
    const int* __restrict__ tmp, const int* __restrict__ gbcursor,
    const uint4* __restrict__ h1s4, const float* __restrict__ dinv,
    const float* __restrict__ b1, const float* __restrict__ W2,
    int* __restrict__ row_start, int* __restrict__ degs, int* __restrict__ csr,
    unsigned* __restrict__ t, int n) {
  __shared__ int lcsr[CAPP];       // 37KB
  __shared__ int nh[512];
  __shared__ int rs_s[512];
  __shared__ int lcur[512];
  __shared__ float W2s[64 * 17];
  __shared__ float b1s[64];
  __shared__ float a_s[16][2][64];
  int b = blockIdx.x, tid = threadIdx.x;
  int base = b * CAP;
  int count = min(gbcursor[b] - base, CAP);

  if (tid < 512) nh[tid] = 0;
  W2s[(tid >> 4) * 17 + (tid & 15)] = W2[tid];   // 1024 == 64*16
  if (tid < 64) b1s[tid] = b1[tid];
  __syncthreads();
  // histogram
  for (int i = tid; i < count; i += 1024) atomicAdd(&nh[tmp[base + i] & BMASK], 1);
  __syncthreads();
  // exclusive scan of nh over 512
  int d = 0;
  if (tid < 512) { d = nh[tid]; rs_s[tid] = d; }
  __syncthreads();
  for (int off = 1; off < 512; off <<= 1) {
    int a = 0;
    if (tid < 512) { a = rs_s[tid]; if (tid >= off) a += rs_s[tid - off]; }
    __syncthreads();
    if (tid < 512) rs_s[tid] = a;
    __syncthreads();
  }
  if (tid < 512) {
    int e0 = rs_s[tid] - d;   // exclusive prefix (bucket-local)
    lcur[tid] = e0;
    rs_s[tid] = e0;
    int v = (b << BSHIFT) + tid;
    if (v < n) { row_start[v] = base + e0; degs[v] = d; }
  }
  __syncthreads();
  // scatter into LDS csr
  for (int i = tid; i < count; i += 1024) {
    int val = tmp[base + i];
    int pos = atomicAdd(&lcur[val & BMASK], 1);
    lcsr[pos] = val >> BSHIFT;
  }
  __syncthreads();
  // coalesced dump for agg2
  for (int i = tid; i < count; i += 1024) csr[base + i] = lcsr[i];

  // walk
  int wave = tid >> 6, lane = tid & 63;
  int half = lane >> 5, sub = lane & 31;
  int e = sub >> 3, c = sub & 7;
  int j = sub & 15, grp = (sub >> 4) & 1;

#pragma unroll 1
  for (int it = 0; it < 16; ++it) {
    int nl = wave * 32 + it * 2 + half;       // 0..511
    int v = (b << BSHIFT) + nl;
    bool valid = (v < n);                     // half-uniform
    int rs = rs_s[nl];
    int deg = nh[nl];                         // 0 for v >= n
    int e1 = rs + deg;
    float dv = valid ? dinv[valid ? v : 0] : 0.f;

    f2 a0[4];
#pragma unroll
    for (int k = 0; k < 4; ++k) a0[k] = {0.f, 0.f};
    {  // self loop: e==0 lanes pull row v, others pull zero row
      int s = (valid && sub < 8) ? v : n;
      addu4(a0, h1s4[(size_t)s * 8 + c]);
    }
    // fast path deg<=32: all csr entries up front (LDS), 8 independent gathers
    int cv0[4], cv1[4];
#pragma unroll
    for (int q = 0; q < 4; ++q) {
      cv0[q] = lcsr[rs + q * 8 + e];
      cv1[q] = lcsr[rs + q * 8 + 4 + e];
    }
    uint4 g[8];
#pragma unroll
    for (int q = 0; q < 4; ++q) {
      int k0 = rs + q * 8 + e, k1 = k0 + 4;
      int s0 = (k0 < e1) ? cv0[q] : n;
      int s1 = (k1 < e1) ? cv1[q] : n;
      g[2 * q] = h1s4[(size_t)s0 * 8 + c];
      g[2 * q + 1] = h1s4[(size_t)s1 * 8 + c];
    }
#pragma unroll
    for (int k = 0; k < 8; ++k) addu4(a0, g[k]);
    // tail: deg > 32 (rare)
    int i = rs + 32;
    while (__any(i < e1)) {
      int i0 = i + e, i1 = i + 4 + e;
      int s0v = lcsr[i0];
      int s1v = lcsr[i1];
      int s0 = (i0 < e1) ? s0v : n;
      int s1 = (i1 < e1) ? s1v : n;
      addu4(a0, h1s4[(size_t)s0 * 8 + c]);
      addu4(a0, h1s4[(size_t)s1 * 8 + c]);
      i += 8;
    }
    // reduce across e (lane bits 3,4 within half)
#pragma unroll
    for (int m = 8; m <= 16; m <<= 1) {
#pragma unroll
      for (int k = 0; k < 4; ++k) {
        a0[k].x += __shfl_xor(a0[k].x, m, 64);
        a0[k].y += __shfl_xor(a0[k].y, m, 64);
      }
    }
    if (sub < 8) {  // e==0; c==sub; features 8c..8c+7
#pragma unroll
      for (int k = 0; k < 4; ++k) {
        float z0 = fmaf(dv, a0[k].x, b1s[8 * sub + 2 * k]);
        float z1 = fmaf(dv, a0[k].y, b1s[8 * sub + 2 * k + 1]);
        a_s[wave][half][8 * sub + 2 * k] = fmaxf(z0, 0.2f * z0);
        a_s[wave][half][8 * sub + 2 * k + 1] = fmaxf(z1, 0.2f * z1);
      }
    }
    // MLP 64->16: each half-lane sums 32 features (grp*16 and 32+grp*16)
    float p = 0.f;
#pragma unroll
    for (int q = 0; q < 16; ++q) {
      int f = grp * 16 + q;
      p = fmaf(a_s[wave][half][f], W2s[f * 17 + j], p);
    }
#pragma unroll
    for (int q = 0; q < 16; ++q) {
      int f = 32 + grp * 16 + q;
      p = fmaf(a_s[wave][half][f], W2s[f * 17 + j], p);
    }
    p += __shfl_xor(p, 16, 64);  // combine grp halves (lane bit 4)
    float pv = dv * p;
    float po = __shfl_xor(pv, 1, 64);
    if (valid && sub < 16 && !(sub & 1))
      t[(size_t)v * 8 + (sub >> 1)] = (f2b(po) << 16) | f2b(pv);
  }
}

// 16 lanes per node, bf16 t rows (32B). sub=lane&15: e=sub>>1, c=sub&1.
// Fast path deg<=32: 4 csr loads + 4 independent gathers. Padded csr layout.
__global__ __launch_bounds__(256) void agg2_kernel(const uint4* __restrict__ t4,
                                                   const float* __restrict__ dinv,
                                                   const int* __restrict__ row_start,
                                                   const int* __restrict__ degs,
                                                   const int* __restrict__ csr,
                                                   const float* __restrict__ b2,
                                                   float* __restrict__ out, int n) {
  int idx = blockIdx.x * 256 + threadIdx.x;
  int v = idx >> 4;
  if (v >= n) return;
  int sub = threadIdx.x & 15;
  int e = sub >> 1, c = sub & 1;
  float dv = dinv[v];
  int rs = row_start[v], e1 = rs + degs[v];
  f2 A0[4];
#pragma unroll
  for (int k = 0; k < 4; ++k) A0[k] = {0.f, 0.f};
  {  // self loop
    int s = (e == 0) ? v : n;
    addu4(A0, t4[(size_t)s * 2 + c]);
  }
  int cv[4];
#pragma unroll
  for (int q = 0; q < 4; ++q) cv[q] = csr[rs + q * 8 + e];
  uint4 g[4];
#pragma unroll
  for (int q = 0; q < 4; ++q) {
    int k = rs + q * 8 + e;
    int s = (k < e1) ? cv[q] : n;
    g[q] = t4[(size_t)s * 2 + c];
  }
#pragma unroll
  for (int k = 0; k < 4; ++k) addu4(A0, g[k]);
  // tail: deg > 32 (rare; node-uniform)
  int i = rs + 32;
  while (i < e1) {
    int i0 = i + e;
    int sv = csr[i0];
    int s = (i0 < e1) ? sv : n;
    addu4(A0, t4[(size_t)s * 2 + c]);
    i += 8;
  }
#pragma unroll
  for (int m = 2; m <= 8; m <<= 1) {  // reduce across e-groups (sub bits 1..3)
#pragma unroll
    for (int k = 0; k < 4; ++k) {
      A0[k].x += __shfl_xor(A0[k].x, m, 64);
      A0[k].y += __shfl_xor(A0[k].y, m, 64);
    }
  }
  float4 bb0 = ((const float4*)b2)[c * 2];
  float4 bb1 = ((const float4*)b2)[c * 2 + 1];
  float z[8];
  z[0] = fmaf(dv, A0[0].x, bb0.x); z[1] = fmaf(dv, A0[0].y, bb0.y);
  z[2] = fmaf(dv, A0[1].x, bb0.z); z[3] = fmaf(dv, A0[1].y, bb0.w);
  z[4] = fmaf(dv, A0[2].x, bb1.x); z[5] = fmaf(dv, A0[2].y, bb1.y);
  z[6] = fmaf(dv, A0[3].x, bb1.z); z[7] = fmaf(dv, A0[3].y, bb1.w);
  float mx = z[0];
#pragma unroll
  for (int q = 1; q < 8; ++q) mx = fmaxf(mx, z[q]);
  mx = fmaxf(mx, __shfl_xor(mx, 1, 64));  // combine c halves
  float ss = 0.f;
#pragma unroll
  for (int q = 0; q < 8; ++q) ss += expf(z[q] - mx);
  ss += __shfl_xor(ss, 1, 64);
  float lg = mx + logf(ss);
  if (e == 0) {
    float4 r0 = make_float4(z[0] - lg, z[1] - lg, z[2] - lg, z[3] - lg);
    float4 r1 = make_float4(z[4] - lg, z[5] - lg, z[6] - lg, z[7] - lg);
    float4* o = (float4*)out + (size_t)v * 4 + c * 2;
    o[0] = r0;
    o[1] = r1;
  }
}

extern "C" void kernel_launch(void* const* d_in, const int* in_sizes, int n_in,
                              void* d_out, int out_size, void* d_ws, size_t ws_size,
                              hipStream_t stream) {
  const float* x = (const float*)d_in[0];
  const int* edge_index = (const int*)d_in[1];
  const float* W1 = (const float*)d_in[2];
  const float* b1 = (const float*)d_in[3];
  const float* W2 = (const float*)d_in[4];
  const float* b2 = (const float*)d_in[5];
  float* out = (float*)d_out;

  int N_ = in_sizes[0] / 128;
  int E_ = in_sizes[1] / 2;
  const int* src = edge_index;
  const int* dst = edge_index + E_;
  int NBc = (N_ + BMASK) >> BSHIFT;  // 196 buckets of 512 nodes (<= 256)

  char* ws = (char*)d_ws;
  size_t off = 0;
  auto take = [&](size_t bytes) {
    void* p = ws + off;
    off += (bytes + 255) & ~(size_t)255;
    return p;
  };
  unsigned* h1s = (unsigned*)take(((size_t)N_ + 1) * 32 * 4);  // +1 zero row
  unsigned* t = (unsigned*)take(((size_t)N_ + 1) * 8 * 4);     // +1 zero row
  int* tmp = (int*)take((size_t)NBc * CAP * 4);
  int* csr = (int*)take(((size_t)NBc * CAP + 64) * 4);         // padded layout
  float* dinv = (float*)take((size_t)N_ * 4);
  int* degs = (int*)take((size_t)N_ * 4);
  int* row_start = (int*)take((size_t)N_ * 4);
  int* gbcursor = (int*)take((size_t)NBc * 4);
  (void)ws_size;

  binit_kernel<<<(NBc + 255) / 256, 256, 0, stream>>>(gbcursor, NBc, h1s, t, N_);
  scatterA_kernel<<<(E_ + CHUNK - 1) / CHUNK, 256, 0, stream>>>(src, dst, E_, NBc,
                                                                gbcursor, tmp);
  degcnt_kernel<<<NBc, 512, 0, stream>>>(tmp, gbcursor, dinv, N_);
  gemm1_kernel<<<(N_ + 63) / 64, 256, 0, stream>>>(x, W1, dinv, h1s, N_);
  agg1_fused_kernel<<<NBc, 1024, 0, stream>>>(tmp, gbcursor, (const uint4*)h1s,
                                              dinv, b1, W2, row_start, degs, csr,
                                              t, N_);
  agg2_kernel<<<(N_ * 16 + 255) / 256, 256, 0, stream>>>((const uint4*)t, dinv,
                                                         row_start, degs, csr,
                                                         b2, out, N_);
}